// Round 1
// baseline (153.667 us; speedup 1.0000x reference)
//
#include <hip/hip_runtime.h>

#define BATCH   1024
#define GROUPS  512
#define OUT_DIM 64
#define G_TILE  4      // groups per block
#define B_TILE  32     // batches per block

typedef float f32x4 __attribute__((ext_vector_type(4)));

// Block = 4 groups x 32 batches. 4 param tables (16 KiB) staged linearly in
// LDS. Lane layout: gl=(tid>>4)&3 (group), c4=tid&15 (float4 column of D=64),
// w=tid>>6 (wave -> batch). Each lane computes ONE output float4, so a wave's
// 64 lanes store O[b][g0..g0+3][0..63] = one contiguous, 1KiB-aligned 1KiB
// burst per store instruction (vs 8x128B segments strided 128KiB before).
// LDS reads: each 16-lane group reads a contiguous 256B row slice -> covers
// all 32 banks exactly twice -> conflict-free for ANY data-dependent row.
__global__ __launch_bounds__(256) void hoact_kernel(
    const float4* __restrict__ X4,   // [B*G]       (4 f32 -> one float4)
    const float4* __restrict__ P4,   // [G*256]     (16 rows x 16 float4)
    float4*       __restrict__ O4)   // [B*G*16]
{
    __shared__ float tbl[G_TILE * 16 * 64];   // 16 KiB, linear == params layout

    const int gtile  = blockIdx.x & 127;      // consecutive blocks = consecutive
    const int bchunk = blockIdx.x >> 7;       // g-tiles -> contiguous output rows
    const int g0     = gtile * G_TILE;
    const int b0     = bchunk * B_TILE;
    const int tid    = threadIdx.x;

    // ---- stage params for 4 groups: 1024 float4, fully coalesced, linear ----
#pragma unroll
    for (int k = 0; k < 4; ++k) {
        const int q = tid + k * 256;          // float4 slot
        *(f32x4*)&tbl[q * 4] = *(const f32x4*)&P4[g0 * 256 + q];
    }

    const int w        = tid >> 6;            // wave 0..3 -> batch offset
    const int gl       = (tid >> 4) & 3;      // group within tile
    const int c4       = tid & 15;            // float4 column within D=64
    const int lane64   = tid & 63;            // gl*16 + c4
    const int lds_base = gl * 1024;           // word offset of this group's table

    // ---- prefetch X for all 8 passes (wave reads 64B contiguous, 16-lane bcast) ----
    float4 xv[8];
#pragma unroll
    for (int p = 0; p < 8; ++p) {
        const int b = b0 + p * 4 + w;
        xv[p] = X4[b * GROUPS + g0 + gl];
    }

    __syncthreads();

#pragma unroll
    for (int p = 0; p < 8; ++p) {
        const int b = b0 + p * 4 + w;
        const float4 x = xv[p];

        // pack 2-bit source index into mantissa LSBs (<=3 ULP, harmless vs
        // 0.0625 threshold); sort via fmin/fmax network; ties -> zero gap coef.
        float v0 = __uint_as_float((__float_as_uint(x.x) & ~3u) | 0u);
        float v1 = __uint_as_float((__float_as_uint(x.y) & ~3u) | 1u);
        float v2 = __uint_as_float((__float_as_uint(x.z) & ~3u) | 2u);
        float v3 = __uint_as_float((__float_as_uint(x.w) & ~3u) | 3u);

#define CSWAP(a, b_)                                 \
        {                                            \
            const float lo = fminf((a), (b_));       \
            const float hi = fmaxf((a), (b_));       \
            (a) = lo; (b_) = hi;                     \
        }
        CSWAP(v0, v1);
        CSWAP(v2, v3);
        CSWAP(v0, v2);
        CSWAP(v1, v3);
        CSWAP(v1, v2);
#undef CSWAP

        const int i1 = __float_as_uint(v1) & 3;
        const int i2 = __float_as_uint(v2) & 3;
        const int i3 = __float_as_uint(v3) & 3;

        const float c0 = v0;
        const float c1 = v1 - v0;
        const float c2 = v2 - v1;
        const float c3 = v3 - v2;

        const int e3 = 1 << i3;
        const int e2 = e3 + (1 << i2);
        const int e1 = e2 + (1 << i1);
        // e0 == 15 always

        // one float4 column per lane; 16-lane group reads contiguous 256B rows
        const f32x4 p0 = *(const f32x4*)&tbl[lds_base + 15 * 64 + c4 * 4];
        const f32x4 p1 = *(const f32x4*)&tbl[lds_base + e1 * 64 + c4 * 4];
        const f32x4 p2 = *(const f32x4*)&tbl[lds_base + e2 * 64 + c4 * 4];
        const f32x4 p3 = *(const f32x4*)&tbl[lds_base + e3 * 64 + c4 * 4];

        f32x4 o;
        o.x = c0 * p0.x + c1 * p1.x + c2 * p2.x + c3 * p3.x;
        o.y = c0 * p0.y + c1 * p1.y + c2 * p2.y + c3 * p3.y;
        o.z = c0 * p0.z + c1 * p1.z + c2 * p2.z + c3 * p3.z;
        o.w = c0 * p0.w + c1 * p1.w + c2 * p2.w + c3 * p3.w;

        // wave writes O[b][g0:g0+4][:] = 1 KiB contiguous, 1 KiB aligned.
        // nontemporal: 134 MB stream must not evict the 2 MB param set from L2.
        const int o_idx = b * (GROUPS * 16) + gtile * 64 + lane64;
        __builtin_nontemporal_store(o, (f32x4*)&O4[o_idx]);
    }
}

extern "C" void kernel_launch(void* const* d_in, const int* in_sizes, int n_in,
                              void* d_out, int out_size, void* d_ws, size_t ws_size,
                              hipStream_t stream) {
    const float4* X4 = (const float4*)d_in[0];   // X: [1024, 512, 4] fp32
    const float4* P4 = (const float4*)d_in[1];   // params: [512, 16, 64] fp32
    float4*       O4 = (float4*)d_out;           // out: [1024, 512, 64] fp32

    const int grid = (GROUPS / G_TILE) * (BATCH / B_TILE);   // 128 * 32 = 4096
    hipLaunchKernelGGL(hoact_kernel, dim3(grid), dim3(256), 0, stream,
                       X4, P4, O4);
}